// Round 9
// baseline (956.499 us; speedup 1.0000x reference)
//
#include <hip/hip_runtime.h>

#define N_NODES  131072
#define N_GRAPHS 4096
#define HID      512

typedef float  f32x4  __attribute__((ext_vector_type(4)));
typedef __bf16 bf16x8 __attribute__((ext_vector_type(8)));
typedef unsigned short u16x8 __attribute__((ext_vector_type(8)));

__device__ __forceinline__ unsigned short f2bf(float f) {
  unsigned int u = __builtin_bit_cast(unsigned int, f);
  u += 0x7FFFu + ((u >> 16) & 1u);   // round-to-nearest-even
  return (unsigned short)(u >> 16);
}
__device__ __forceinline__ f32x4 mfma_bf16(bf16x8 a, bf16x8 b, f32x4 c) {
  return __builtin_amdgcn_mfma_f32_16x16x32_bf16(a, b, c, 0, 0, 0);
}
__device__ __forceinline__ bf16x8 cvt8(float4 p0, float4 p1) {
  u16x8 u;
  u[0]=f2bf(p0.x); u[1]=f2bf(p0.y); u[2]=f2bf(p0.z); u[3]=f2bf(p0.w);
  u[4]=f2bf(p1.x); u[5]=f2bf(p1.y); u[6]=f2bf(p1.z); u[7]=f2bf(p1.w);
  return __builtin_bit_cast(bf16x8, u);
}

// ---------- bucket: sort graphs by branch (graph path only) ----------
__global__ __launch_bounds__(256) void bucket_kernel(
    const int* __restrict__ dsid, int* __restrict__ perm, int* __restrict__ meta) {
  __shared__ int cnt[4], base[4], off[4];
  int t = threadIdx.x;
  if (t < 4) { cnt[t] = 0; off[t] = 0; }
  __syncthreads();
  for (int g = t; g < N_GRAPHS; g += 256) atomicAdd(&cnt[dsid[g]], 1);
  __syncthreads();
  if (t == 0) {
    int s = 0;
    for (int b = 0; b < 4; ++b) { base[b] = s; s += cnt[b]; meta[b] = cnt[b]; }
  }
  __syncthreads();
  for (int g = t; g < N_GRAPHS; g += 256) {
    int b = dsid[g];
    int p = base[b] + atomicAdd(&off[b], 1);
    perm[p] = g;
  }
}

// ---------- prep: W[b][k][n] fp32 -> fragment-ordered bf16 -------------------
// [b][hf=32][kk=16][lane=64][e=8]; value = W[k=kk*32+(lane>>4)*8+e][n=hf*16+(lane&15)]
__global__ __launch_bounds__(256) void prep_wf_kernel(
    const float* __restrict__ Wn1, const float* __restrict__ Ws,
    unsigned short* __restrict__ W1Tf, unsigned short* __restrict__ WsTf) {
  __shared__ unsigned short lt[8192];
  const int bid = blockIdx.x;          // 256 blocks
  const int which = bid >> 7;
  const int b  = (bid >> 5) & 3;
  const int hf = bid & 31;
  const float* src = (which ? Ws : Wn1) + (size_t)b * 512 * 512 + hf * 16;
  unsigned short* dst = (which ? WsTf : W1Tf) + (size_t)(b * 32 + hf) * 8192;
  const int t = threadIdx.x;
  for (int i = t; i < 8192; i += 256) {
    int k = i >> 4;
    int n = i & 15;
    float v = src[(size_t)k * 512 + n];
    int kk = k >> 5, lane = n + ((k >> 3) & 3) * 16, e = k & 7;
    lt[(kk * 64 + lane) * 8 + e] = f2bf(v);
  }
  __syncthreads();
  u16x8* d8 = (u16x8*)dst;
  const u16x8* s8 = (const u16x8*)lt;
  for (int i = t; i < 1024; i += 256) d8[i] = s8[i];
}

// ---------- prep: Wg (4,512,100) -> WgT [b][128][512] bf16 zero-pad ----------
__global__ __launch_bounds__(256) void prep_wg_kernel(
    const float* __restrict__ Wg, unsigned short* __restrict__ WgT) {
  int idx = blockIdx.x * 256 + threadIdx.x;   // 1024 blocks
  int b = idx >> 16;
  int r = (idx >> 9) & 127;
  int k = idx & 511;
  float v = (r < 100) ? Wg[(b * 512 + k) * 100 + r] : 0.f;
  WgT[idx] = f2bf(v);
}

// ---------- node kernel: 1 block = 1 graph, NO x-staging ---------------------
// Swapped roles: A = x-fragment loaded DIRECTLY from global fp32 (2 float4/lane),
// B = W-fragment from L2. 512 thr / 8 waves, wave owns 64 hcols -> acc[2][4]=32 AGPR.
// D[node][hcol]: node = nf*16 + l4*4 + r, hcol = (w*4+h)*16 + l15.
// No barriers in K-loop, LDS only for the 6KB stage-2 reduce. 4 blocks/CU.
__global__ __launch_bounds__(512, 8) void node_kernel(
    const float* __restrict__ x,
    const int* __restrict__ dsid,
    const unsigned short* __restrict__ W1Tf,
    const float* __restrict__ bn1,
    const float* __restrict__ Wn2,
    const float* __restrict__ bn2,
    unsigned short* __restrict__ xg,
    float* __restrict__ n_head,
    float* __restrict__ n_var) {
  __shared__ __align__(16) float red[8][32][6];   // 6 KB

  const int g = blockIdx.x;
  const int b = dsid[g];
  const int t = threadIdx.x;
  const int lane = t & 63, w = t >> 6, l15 = lane & 15, l4 = lane >> 4;

  // A source: lane reads x[g*32 + nf*16 + l15][kk*32 + l4*8 .. +8]
  const float* xA = x + ((size_t)g * 32 + l15) * HID + l4 * 8;
  // B source: [b][hf=w*4+h][kk][lane][e]
  const unsigned short* wB = W1Tf + ((size_t)(b * 32 + w * 4)) * 8192 + lane * 8;

  f32x4 acc[2][4];
  #pragma unroll
  for (int m = 0; m < 2; ++m)
    #pragma unroll
    for (int n = 0; n < 4; ++n) acc[m][n] = (f32x4)0.f;

  #pragma unroll
  for (int kk = 0; kk < 16; ++kk) {
    float4 a00 = *(const float4*)(xA + kk * 32);
    float4 a01 = *(const float4*)(xA + kk * 32 + 4);
    float4 a10 = *(const float4*)(xA + 16 * HID + kk * 32);
    float4 a11 = *(const float4*)(xA + 16 * HID + kk * 32 + 4);
    bf16x8 bf[4];
    #pragma unroll
    for (int h = 0; h < 4; ++h)
      bf[h] = *(const bf16x8*)(wB + (size_t)h * 8192 + kk * 512);
    bf16x8 a0 = cvt8(a00, a01);
    bf16x8 a1 = cvt8(a10, a11);
    #pragma unroll
    for (int h = 0; h < 4; ++h) {
      acc[0][h] = mfma_bf16(a0, bf[h], acc[0][h]);
      acc[1][h] = mfma_bf16(a1, bf[h], acc[1][h]);
    }
  }

  // ---- pool: column sums (L1-hot after K-loop), thread t owns column t ----
  {
    const float* xc = x + (size_t)g * 32 * HID + t;
    float sv = 0.f;
    #pragma unroll 8
    for (int r = 0; r < 32; ++r) sv += xc[(size_t)r * HID];
    xg[(size_t)g * HID + t] = f2bf(sv * (1.f / 32.f));
  }

  // ---- fused stage 2: per-lane dot over this lane's 4 hcols ----
  float part[8][6];   // row slot = nf*4 + r
  #pragma unroll
  for (int s = 0; s < 8; ++s)
    #pragma unroll
    for (int j = 0; j < 6; ++j) part[s][j] = 0.f;
  const float* B1 = bn1 + b * HID;
  const float* W2 = Wn2 + b * HID * 6;
  #pragma unroll
  for (int h = 0; h < 4; ++h) {
    int hcol = (w * 4 + h) * 16 + l15;
    float b1 = B1[hcol];
    float w2[6];
    #pragma unroll
    for (int j = 0; j < 6; ++j) w2[j] = W2[hcol * 6 + j];
    #pragma unroll
    for (int nf = 0; nf < 2; ++nf)
      #pragma unroll
      for (int r = 0; r < 4; ++r) {
        float hv = fmaxf(acc[nf][h][r] + b1, 0.f);
        #pragma unroll
        for (int j = 0; j < 6; ++j) part[nf * 4 + r][j] += hv * w2[j];
      }
  }
  // reduce over l15 (16-lane groups; l4 encodes the node row -> do NOT cross)
  #pragma unroll
  for (int s = 0; s < 8; ++s)
    #pragma unroll
    for (int j = 0; j < 6; ++j) {
      part[s][j] += __shfl_xor(part[s][j], 1);
      part[s][j] += __shfl_xor(part[s][j], 2);
      part[s][j] += __shfl_xor(part[s][j], 4);
      part[s][j] += __shfl_xor(part[s][j], 8);
    }
  if (l15 == 0) {
    #pragma unroll
    for (int nf = 0; nf < 2; ++nf)
      #pragma unroll
      for (int r = 0; r < 4; ++r)
        #pragma unroll
        for (int j = 0; j < 6; ++j)
          red[w][nf * 16 + l4 * 4 + r][j] = part[nf * 4 + r][j];
  }
  __syncthreads();
  if (t < 32) {
    int node = g * 32 + t;
    #pragma unroll
    for (int j = 0; j < 6; ++j) {
      float sv = bn2[b * 6 + j];
      #pragma unroll
      for (int ww = 0; ww < 8; ++ww) sv += red[ww][t][j];
      if (j < 3) n_head[(size_t)node * 3 + j] = sv;
      else       n_var[(size_t)node * 3 + (j - 3)] = sv * sv;
    }
  }
}

// ---------- graph stage-1: hg = relu(xg @ Ws + bs), 64 graphs/block ----------
#define GT_MAX 67
__global__ __launch_bounds__(512, 4) void gstage1_kernel(
    const unsigned short* __restrict__ xg,
    const int* __restrict__ meta,
    const int* __restrict__ perm,
    const unsigned short* __restrict__ WsTf,
    const float* __restrict__ bs_,
    unsigned short* __restrict__ hg) {
  __shared__ __align__(16) unsigned short xtile[32768];
  __shared__ int gidl[64];

  const int4 cv = *(const int4*)meta;
  const int cnts[4] = {cv.x, cv.y, cv.z, cv.w};

  int i = blockIdx.x, branch = -1, permOff = 0, nvalid = 0, pb = 0;
  for (int b = 0; b < 4; ++b) {
    int gt = (cnts[b] + 63) >> 6;
    if (branch < 0 && i < gt) { branch = b; permOff = pb + i * 64; nvalid = min(64, cnts[b] - i * 64); }
    if (branch < 0) i -= gt;
    pb += cnts[b];
  }
  if (branch < 0) return;

  const int t = threadIdx.x;
  const int lane = t & 63, w = t >> 6, l15 = lane & 15, l4 = lane >> 4;

  if (t < 64) gidl[t] = perm[permOff + min(t, nvalid - 1)];
  __syncthreads();

  for (int idx = t; idx < 4096; idx += 512) {
    int row = idx >> 6;
    int c8  = (idx & 63) * 8;
    u16x8 v = *(const u16x8*)&xg[(size_t)gidl[row] * HID + c8];
    int kk = c8 >> 5, ln = (c8 >> 3) & 3;
    *(u16x8*)&xtile[(((row >> 4) * 16 + kk) * 64 + ((row & 15) + ln * 16)) * 8] = v;
  }
  __syncthreads();

  f32x4 acc[4][4];
  #pragma unroll
  for (int m = 0; m < 4; ++m)
    #pragma unroll
    for (int n = 0; n < 4; ++n) acc[m][n] = (f32x4)0.f;

  const unsigned short* wbase = WsTf + ((size_t)(branch * 32 + w * 4)) * 8192 + lane * 8;
  const unsigned short* xbase = xtile + lane * 8;
  #pragma unroll
  for (int kk = 0; kk < 16; ++kk) {
    bf16x8 af[4];
    #pragma unroll
    for (int m = 0; m < 4; ++m)
      af[m] = *(const bf16x8*)(wbase + (m * 16 + kk) * 512);
    bf16x8 bfr[4];
    #pragma unroll
    for (int n = 0; n < 4; ++n)
      bfr[n] = *(const bf16x8*)(xbase + (n * 16 + kk) * 512);
    #pragma unroll
    for (int m = 0; m < 4; ++m)
      #pragma unroll
      for (int n = 0; n < 4; ++n)
        acc[m][n] = mfma_bf16(af[m], bfr[n], acc[m][n]);
  }

  const float* B1 = bs_ + branch * HID;
  #pragma unroll
  for (int m = 0; m < 4; ++m) {
    #pragma unroll
    for (int n = 0; n < 4; ++n) {
      int row = n * 16 + l15;
      if (row < nvalid) {
        int g = gidl[row];
        int hcb = w * 64 + m * 16 + l4 * 4;
        ushort4 hv;
        hv.x = f2bf(fmaxf(acc[m][n][0] + B1[hcb + 0], 0.f));
        hv.y = f2bf(fmaxf(acc[m][n][1] + B1[hcb + 1], 0.f));
        hv.z = f2bf(fmaxf(acc[m][n][2] + B1[hcb + 2], 0.f));
        hv.w = f2bf(fmaxf(acc[m][n][3] + B1[hcb + 3], 0.f));
        *(ushort4*)(hg + (size_t)g * HID + hcb) = hv;
      }
    }
  }
}

// ---------- graph stage-2: og = hg @ Wg[b] + bg, 16 graphs/block -------------
#define G2_MAX 259
__global__ __launch_bounds__(256) void gstage2_kernel(
    const int* __restrict__ meta,
    const int* __restrict__ perm,
    const unsigned short* __restrict__ hg,
    const unsigned short* __restrict__ WgT,
    const float* __restrict__ bg,
    float* __restrict__ g_head,
    float* __restrict__ g_var) {
  __shared__ int gidl[16];
  const int4 cv = *(const int4*)meta;
  const int cnts[4] = {cv.x, cv.y, cv.z, cv.w};

  int i = blockIdx.x, branch = -1, permOff = 0, nvalid = 0, pb = 0;
  for (int b = 0; b < 4; ++b) {
    int gt = (cnts[b] + 15) >> 4;
    if (branch < 0 && i < gt) { branch = b; permOff = pb + i * 16; nvalid = min(16, cnts[b] - i * 16); }
    if (branch < 0) i -= gt;
    pb += cnts[b];
  }
  if (branch < 0) return;

  const int t = threadIdx.x;
  const int lane = t & 63, w = t >> 6, l15 = lane & 15, l4 = lane >> 4;

  if (t < 16) gidl[t] = perm[permOff + min(t, nvalid - 1)];
  __syncthreads();

  f32x4 acc2[2];
  acc2[0] = (f32x4)0.f; acc2[1] = (f32x4)0.f;
  const unsigned short* arow = hg + (size_t)gidl[l15] * HID + l4 * 8;
  const unsigned short* brow = WgT + ((size_t)branch * 128 + w * 32 + l15) * 512 + l4 * 8;
  #pragma unroll
  for (int ks = 0; ks < 16; ++ks) {
    bf16x8 a  = *(const bf16x8*)(arow + ks * 32);
    bf16x8 b0 = *(const bf16x8*)(brow + ks * 32);
    bf16x8 b1 = *(const bf16x8*)(brow + 16 * 512 + ks * 32);
    acc2[0] = mfma_bf16(a, b0, acc2[0]);
    acc2[1] = mfma_bf16(a, b1, acc2[1]);
  }
  #pragma unroll
  for (int n2 = 0; n2 < 2; ++n2) {
    int j = w * 32 + n2 * 16 + l15;
    if (j < 100) {
      float bias = bg[branch * 100 + j];
      #pragma unroll
      for (int rr = 0; rr < 4; ++rr) {
        int r = l4 * 4 + rr;
        if (r < nvalid) {
          int g = gidl[r];
          float val = acc2[n2][rr] + bias;
          if (j < 50) g_head[(size_t)g * 50 + j] = val;
          else        g_var[(size_t)g * 50 + (j - 50)] = val * val;
        }
      }
    }
  }
}

extern "C" void kernel_launch(void* const* d_in, const int* in_sizes, int n_in,
                              void* d_out, int out_size, void* d_ws, size_t ws_size,
                              hipStream_t stream) {
  const float* x    = (const float*)d_in[0];
  const float* Ws   = (const float*)d_in[1];
  const float* bs   = (const float*)d_in[2];
  const float* Wg   = (const float*)d_in[3];
  const float* bg   = (const float*)d_in[4];
  const float* Wn1  = (const float*)d_in[5];
  const float* bn1  = (const float*)d_in[6];
  const float* Wn2  = (const float*)d_in[7];
  const float* bn2  = (const float*)d_in[8];
  const int* dsid   = (const int*)d_in[10];

  float* out    = (float*)d_out;
  float* g_head = out;
  float* g_var  = out + (size_t)N_GRAPHS * 50;
  float* n_head = out + (size_t)2 * N_GRAPHS * 50;
  float* n_var  = n_head + (size_t)N_NODES * 3;

  char* ws = (char*)d_ws;
  int* perm = (int*)(ws);                                   // 16,384
  int* meta = (int*)(ws + 16384);                           // 256
  unsigned short* W1Tf = (unsigned short*)(ws + 16640);     // 2,097,152
  unsigned short* WsTf = (unsigned short*)(ws + 2113792);   // 2,097,152
  unsigned short* WgT  = (unsigned short*)(ws + 4210944);   // 524,288
  unsigned short* xg   = (unsigned short*)(ws + 4735232);   // 4,194,304
  unsigned short* hg   = (unsigned short*)(ws + 8929536);   // 4,194,304
  if (ws_size < 13123840) return;

  bucket_kernel<<<dim3(1), dim3(256), 0, stream>>>(dsid, perm, meta);
  prep_wf_kernel<<<dim3(256), dim3(256), 0, stream>>>(Wn1, Ws, W1Tf, WsTf);
  prep_wg_kernel<<<dim3(1024), dim3(256), 0, stream>>>(Wg, WgT);
  node_kernel<<<dim3(N_GRAPHS), dim3(512), 0, stream>>>(
      x, dsid, W1Tf, bn1, Wn2, bn2, xg, n_head, n_var);
  gstage1_kernel<<<dim3(GT_MAX), dim3(512), 0, stream>>>(
      xg, meta, perm, WsTf, bs, hg);
  gstage2_kernel<<<dim3(G2_MAX), dim3(256), 0, stream>>>(
      meta, perm, hg, WgT, bg, g_head, g_var);
}

// Round 10
// 415.834 us; speedup vs baseline: 2.3002x; 2.3002x over previous
//
#include <hip/hip_runtime.h>

#define N_NODES  131072
#define N_GRAPHS 4096
#define HID      512

typedef float  f32x4  __attribute__((ext_vector_type(4)));
typedef float  f32x8  __attribute__((ext_vector_type(8)));
typedef __bf16 bf16x8 __attribute__((ext_vector_type(8)));
typedef unsigned short u16x8 __attribute__((ext_vector_type(8)));

__device__ __forceinline__ unsigned short f2bf(float f) {
  unsigned int u = __builtin_bit_cast(unsigned int, f);
  u += 0x7FFFu + ((u >> 16) & 1u);   // round-to-nearest-even
  return (unsigned short)(u >> 16);
}
__device__ __forceinline__ f32x4 mfma_bf16(bf16x8 a, bf16x8 b, f32x4 c) {
  return __builtin_amdgcn_mfma_f32_16x16x32_bf16(a, b, c, 0, 0, 0);
}
__device__ __forceinline__ bf16x8 cvt8(float4 p0, float4 p1) {
  f32x8 v;
  v[0]=p0.x; v[1]=p0.y; v[2]=p0.z; v[3]=p0.w;
  v[4]=p1.x; v[5]=p1.y; v[6]=p1.z; v[7]=p1.w;
  return __builtin_convertvector(v, bf16x8);   // v_cvt_pk_bf16_f32 x4
}

// ---------- bucket: sort graphs by branch (graph path only) ----------
__global__ __launch_bounds__(256) void bucket_kernel(
    const int* __restrict__ dsid, int* __restrict__ perm, int* __restrict__ meta) {
  __shared__ int cnt[4], base[4], off[4];
  int t = threadIdx.x;
  if (t < 4) { cnt[t] = 0; off[t] = 0; }
  __syncthreads();
  for (int g = t; g < N_GRAPHS; g += 256) atomicAdd(&cnt[dsid[g]], 1);
  __syncthreads();
  if (t == 0) {
    int s = 0;
    for (int b = 0; b < 4; ++b) { base[b] = s; s += cnt[b]; meta[b] = cnt[b]; }
  }
  __syncthreads();
  for (int g = t; g < N_GRAPHS; g += 256) {
    int b = dsid[g];
    int p = base[b] + atomicAdd(&off[b], 1);
    perm[p] = g;
  }
}

// ---------- prep: W[b][k][n] fp32 -> fragment-ordered bf16 -------------------
// [b][hf=32][kk=16][lane=64][e=8]; value = W[k=kk*32+(lane>>4)*8+e][n=hf*16+(lane&15)]
__global__ __launch_bounds__(256) void prep_wf_kernel(
    const float* __restrict__ Wn1, const float* __restrict__ Ws,
    unsigned short* __restrict__ W1Tf, unsigned short* __restrict__ WsTf) {
  __shared__ unsigned short lt[8192];
  const int bid = blockIdx.x;          // 256 blocks
  const int which = bid >> 7;
  const int b  = (bid >> 5) & 3;
  const int hf = bid & 31;
  const float* src = (which ? Ws : Wn1) + (size_t)b * 512 * 512 + hf * 16;
  unsigned short* dst = (which ? WsTf : W1Tf) + (size_t)(b * 32 + hf) * 8192;
  const int t = threadIdx.x;
  for (int i = t; i < 8192; i += 256) {
    int k = i >> 4;
    int n = i & 15;
    float v = src[(size_t)k * 512 + n];
    int kk = k >> 5, lane = n + ((k >> 3) & 3) * 16, e = k & 7;
    lt[(kk * 64 + lane) * 8 + e] = f2bf(v);
  }
  __syncthreads();
  u16x8* d8 = (u16x8*)dst;
  const u16x8* s8 = (const u16x8*)lt;
  for (int i = t; i < 1024; i += 256) d8[i] = s8[i];
}

// ---------- prep: Wg (4,512,100) -> WgT [b][128][512] bf16 zero-pad ----------
__global__ __launch_bounds__(256) void prep_wg_kernel(
    const float* __restrict__ Wg, unsigned short* __restrict__ WgT) {
  int idx = blockIdx.x * 256 + threadIdx.x;   // 1024 blocks
  int b = idx >> 16;
  int r = (idx >> 9) & 127;
  int k = idx & 511;
  float v = (r < 100) ? Wg[(b * 512 + k) * 100 + r] : 0.f;
  WgT[idx] = f2bf(v);
}

// ---------- node kernel: 1 block = 1 graph, NO x-staging ---------------------
// A = x-fragment loaded DIRECTLY from global fp32 (2 float4/lane), B = W from L2.
// 512 thr / 8 waves, wave owns 64 hcols -> acc[2][4] = 32 AGPR.
// D[node][hcol]: node = nf*16 + l4*4 + r, hcol = (w*4+h)*16 + l15.
// (512,4): 128-reg cap, 2 blocks/CU; epilogue split by nf keeps peak ~100 regs.
__global__ __launch_bounds__(512, 4) void node_kernel(
    const float* __restrict__ x,
    const int* __restrict__ dsid,
    const unsigned short* __restrict__ W1Tf,
    const float* __restrict__ bn1,
    const float* __restrict__ Wn2,
    const float* __restrict__ bn2,
    unsigned short* __restrict__ xg,
    float* __restrict__ n_head,
    float* __restrict__ n_var) {
  __shared__ __align__(16) float red[8][32][6];   // 6 KB

  const int g = blockIdx.x;
  const int b = dsid[g];
  const int t = threadIdx.x;
  const int lane = t & 63, w = t >> 6, l15 = lane & 15, l4 = lane >> 4;

  // A source: lane reads x[g*32 + nf*16 + l15][kk*32 + l4*8 .. +8]
  const float* xA = x + ((size_t)g * 32 + l15) * HID + l4 * 8;
  // B source: [b][hf=w*4+h][kk][lane][e]
  const unsigned short* wB = W1Tf + ((size_t)(b * 32 + w * 4)) * 8192 + lane * 8;

  f32x4 acc[2][4];
  #pragma unroll
  for (int m = 0; m < 2; ++m)
    #pragma unroll
    for (int n = 0; n < 4; ++n) acc[m][n] = (f32x4)0.f;

  #pragma unroll
  for (int kk = 0; kk < 16; ++kk) {
    float4 a00 = *(const float4*)(xA + kk * 32);
    float4 a01 = *(const float4*)(xA + kk * 32 + 4);
    float4 a10 = *(const float4*)(xA + 16 * HID + kk * 32);
    float4 a11 = *(const float4*)(xA + 16 * HID + kk * 32 + 4);
    bf16x8 bf[4];
    #pragma unroll
    for (int h = 0; h < 4; ++h)
      bf[h] = *(const bf16x8*)(wB + (size_t)h * 8192 + kk * 512);
    bf16x8 a0 = cvt8(a00, a01);
    bf16x8 a1 = cvt8(a10, a11);
    #pragma unroll
    for (int h = 0; h < 4; ++h) {
      acc[0][h] = mfma_bf16(a0, bf[h], acc[0][h]);
      acc[1][h] = mfma_bf16(a1, bf[h], acc[1][h]);
    }
  }

  // ---- pool: column sums (tile L1/L2-hot after K-loop), thread t owns column t ----
  {
    const float* xc = x + (size_t)g * 32 * HID + t;
    float sv = 0.f;
    #pragma unroll 8
    for (int r = 0; r < 32; ++r) sv += xc[(size_t)r * HID];
    xg[(size_t)g * HID + t] = f2bf(sv * (1.f / 32.f));
  }

  // ---- fused stage 2, split by nf to bound register pressure ----
  const float* B1 = bn1 + b * HID;
  const float* W2 = Wn2 + b * HID * 6;
  #pragma unroll
  for (int nf = 0; nf < 2; ++nf) {
    float part[4][6];
    #pragma unroll
    for (int r = 0; r < 4; ++r)
      #pragma unroll
      for (int j = 0; j < 6; ++j) part[r][j] = 0.f;
    #pragma unroll
    for (int h = 0; h < 4; ++h) {
      int hcol = (w * 4 + h) * 16 + l15;
      float b1 = B1[hcol];
      float w2[6];
      #pragma unroll
      for (int j = 0; j < 6; ++j) w2[j] = W2[hcol * 6 + j];
      #pragma unroll
      for (int r = 0; r < 4; ++r) {
        float hv = fmaxf(acc[nf][h][r] + b1, 0.f);
        #pragma unroll
        for (int j = 0; j < 6; ++j) part[r][j] += hv * w2[j];
      }
    }
    // reduce over l15 (l4 encodes the node row -> do NOT cross 16-lane groups)
    #pragma unroll
    for (int r = 0; r < 4; ++r)
      #pragma unroll
      for (int j = 0; j < 6; ++j) {
        part[r][j] += __shfl_xor(part[r][j], 1);
        part[r][j] += __shfl_xor(part[r][j], 2);
        part[r][j] += __shfl_xor(part[r][j], 4);
        part[r][j] += __shfl_xor(part[r][j], 8);
      }
    if (l15 == 0) {
      #pragma unroll
      for (int r = 0; r < 4; ++r)
        #pragma unroll
        for (int j = 0; j < 6; ++j)
          red[w][nf * 16 + l4 * 4 + r][j] = part[r][j];
    }
  }
  __syncthreads();
  if (t < 32) {
    int node = g * 32 + t;
    #pragma unroll
    for (int j = 0; j < 6; ++j) {
      float sv = bn2[b * 6 + j];
      #pragma unroll
      for (int ww = 0; ww < 8; ++ww) sv += red[ww][t][j];
      if (j < 3) n_head[(size_t)node * 3 + j] = sv;
      else       n_var[(size_t)node * 3 + (j - 3)] = sv * sv;
    }
  }
}

// ---------- graph stage-1: hg = relu(xg @ Ws + bs), 64 graphs/block ----------
#define GT_MAX 67
__global__ __launch_bounds__(512, 4) void gstage1_kernel(
    const unsigned short* __restrict__ xg,
    const int* __restrict__ meta,
    const int* __restrict__ perm,
    const unsigned short* __restrict__ WsTf,
    const float* __restrict__ bs_,
    unsigned short* __restrict__ hg) {
  __shared__ __align__(16) unsigned short xtile[32768];
  __shared__ int gidl[64];

  const int4 cv = *(const int4*)meta;
  const int cnts[4] = {cv.x, cv.y, cv.z, cv.w};

  int i = blockIdx.x, branch = -1, permOff = 0, nvalid = 0, pb = 0;
  for (int b = 0; b < 4; ++b) {
    int gt = (cnts[b] + 63) >> 6;
    if (branch < 0 && i < gt) { branch = b; permOff = pb + i * 64; nvalid = min(64, cnts[b] - i * 64); }
    if (branch < 0) i -= gt;
    pb += cnts[b];
  }
  if (branch < 0) return;

  const int t = threadIdx.x;
  const int lane = t & 63, w = t >> 6, l15 = lane & 15, l4 = lane >> 4;

  if (t < 64) gidl[t] = perm[permOff + min(t, nvalid - 1)];
  __syncthreads();

  for (int idx = t; idx < 4096; idx += 512) {
    int row = idx >> 6;
    int c8  = (idx & 63) * 8;
    u16x8 v = *(const u16x8*)&xg[(size_t)gidl[row] * HID + c8];
    int kk = c8 >> 5, ln = (c8 >> 3) & 3;
    *(u16x8*)&xtile[(((row >> 4) * 16 + kk) * 64 + ((row & 15) + ln * 16)) * 8] = v;
  }
  __syncthreads();

  f32x4 acc[4][4];
  #pragma unroll
  for (int m = 0; m < 4; ++m)
    #pragma unroll
    for (int n = 0; n < 4; ++n) acc[m][n] = (f32x4)0.f;

  const unsigned short* wbase = WsTf + ((size_t)(branch * 32 + w * 4)) * 8192 + lane * 8;
  const unsigned short* xbase = xtile + lane * 8;
  #pragma unroll
  for (int kk = 0; kk < 16; ++kk) {
    bf16x8 af[4];
    #pragma unroll
    for (int m = 0; m < 4; ++m)
      af[m] = *(const bf16x8*)(wbase + (m * 16 + kk) * 512);
    bf16x8 bfr[4];
    #pragma unroll
    for (int n = 0; n < 4; ++n)
      bfr[n] = *(const bf16x8*)(xbase + (n * 16 + kk) * 512);
    #pragma unroll
    for (int m = 0; m < 4; ++m)
      #pragma unroll
      for (int n = 0; n < 4; ++n)
        acc[m][n] = mfma_bf16(af[m], bfr[n], acc[m][n]);
  }

  const float* B1 = bs_ + branch * HID;
  #pragma unroll
  for (int m = 0; m < 4; ++m) {
    #pragma unroll
    for (int n = 0; n < 4; ++n) {
      int row = n * 16 + l15;
      if (row < nvalid) {
        int g = gidl[row];
        int hcb = w * 64 + m * 16 + l4 * 4;
        ushort4 hv;
        hv.x = f2bf(fmaxf(acc[m][n][0] + B1[hcb + 0], 0.f));
        hv.y = f2bf(fmaxf(acc[m][n][1] + B1[hcb + 1], 0.f));
        hv.z = f2bf(fmaxf(acc[m][n][2] + B1[hcb + 2], 0.f));
        hv.w = f2bf(fmaxf(acc[m][n][3] + B1[hcb + 3], 0.f));
        *(ushort4*)(hg + (size_t)g * HID + hcb) = hv;
      }
    }
  }
}

// ---------- graph stage-2: og = hg @ Wg[b] + bg, 16 graphs/block -------------
#define G2_MAX 259
__global__ __launch_bounds__(256) void gstage2_kernel(
    const int* __restrict__ meta,
    const int* __restrict__ perm,
    const unsigned short* __restrict__ hg,
    const unsigned short* __restrict__ WgT,
    const float* __restrict__ bg,
    float* __restrict__ g_head,
    float* __restrict__ g_var) {
  __shared__ int gidl[16];
  const int4 cv = *(const int4*)meta;
  const int cnts[4] = {cv.x, cv.y, cv.z, cv.w};

  int i = blockIdx.x, branch = -1, permOff = 0, nvalid = 0, pb = 0;
  for (int b = 0; b < 4; ++b) {
    int gt = (cnts[b] + 15) >> 4;
    if (branch < 0 && i < gt) { branch = b; permOff = pb + i * 16; nvalid = min(16, cnts[b] - i * 16); }
    if (branch < 0) i -= gt;
    pb += cnts[b];
  }
  if (branch < 0) return;

  const int t = threadIdx.x;
  const int lane = t & 63, w = t >> 6, l15 = lane & 15, l4 = lane >> 4;

  if (t < 16) gidl[t] = perm[permOff + min(t, nvalid - 1)];
  __syncthreads();

  f32x4 acc2[2];
  acc2[0] = (f32x4)0.f; acc2[1] = (f32x4)0.f;
  const unsigned short* arow = hg + (size_t)gidl[l15] * HID + l4 * 8;
  const unsigned short* brow = WgT + ((size_t)branch * 128 + w * 32 + l15) * 512 + l4 * 8;
  #pragma unroll
  for (int ks = 0; ks < 16; ++ks) {
    bf16x8 a  = *(const bf16x8*)(arow + ks * 32);
    bf16x8 b0 = *(const bf16x8*)(brow + ks * 32);
    bf16x8 b1 = *(const bf16x8*)(brow + 16 * 512 + ks * 32);
    acc2[0] = mfma_bf16(a, b0, acc2[0]);
    acc2[1] = mfma_bf16(a, b1, acc2[1]);
  }
  #pragma unroll
  for (int n2 = 0; n2 < 2; ++n2) {
    int j = w * 32 + n2 * 16 + l15;
    if (j < 100) {
      float bias = bg[branch * 100 + j];
      #pragma unroll
      for (int rr = 0; rr < 4; ++rr) {
        int r = l4 * 4 + rr;
        if (r < nvalid) {
          int g = gidl[r];
          float val = acc2[n2][rr] + bias;
          if (j < 50) g_head[(size_t)g * 50 + j] = val;
          else        g_var[(size_t)g * 50 + (j - 50)] = val * val;
        }
      }
    }
  }
}

extern "C" void kernel_launch(void* const* d_in, const int* in_sizes, int n_in,
                              void* d_out, int out_size, void* d_ws, size_t ws_size,
                              hipStream_t stream) {
  const float* x    = (const float*)d_in[0];
  const float* Ws   = (const float*)d_in[1];
  const float* bs   = (const float*)d_in[2];
  const float* Wg   = (const float*)d_in[3];
  const float* bg   = (const float*)d_in[4];
  const float* Wn1  = (const float*)d_in[5];
  const float* bn1  = (const float*)d_in[6];
  const float* Wn2  = (const float*)d_in[7];
  const float* bn2  = (const float*)d_in[8];
  const int* dsid   = (const int*)d_in[10];

  float* out    = (float*)d_out;
  float* g_head = out;
  float* g_var  = out + (size_t)N_GRAPHS * 50;
  float* n_head = out + (size_t)2 * N_GRAPHS * 50;
  float* n_var  = n_head + (size_t)N_NODES * 3;

  char* ws = (char*)d_ws;
  int* perm = (int*)(ws);                                   // 16,384
  int* meta = (int*)(ws + 16384);                           // 256
  unsigned short* W1Tf = (unsigned short*)(ws + 16640);     // 2,097,152
  unsigned short* WsTf = (unsigned short*)(ws + 2113792);   // 2,097,152
  unsigned short* WgT  = (unsigned short*)(ws + 4210944);   // 524,288
  unsigned short* xg   = (unsigned short*)(ws + 4735232);   // 4,194,304
  unsigned short* hg   = (unsigned short*)(ws + 8929536);   // 4,194,304
  if (ws_size < 13123840) return;

  bucket_kernel<<<dim3(1), dim3(256), 0, stream>>>(dsid, perm, meta);
  prep_wf_kernel<<<dim3(256), dim3(256), 0, stream>>>(Wn1, Ws, W1Tf, WsTf);
  prep_wg_kernel<<<dim3(1024), dim3(256), 0, stream>>>(Wg, WgT);
  node_kernel<<<dim3(N_GRAPHS), dim3(512), 0, stream>>>(
      x, dsid, W1Tf, bn1, Wn2, bn2, xg, n_head, n_var);
  gstage1_kernel<<<dim3(GT_MAX), dim3(512), 0, stream>>>(
      xg, meta, perm, WsTf, bs, hg);
  gstage2_kernel<<<dim3(G2_MAX), dim3(256), 0, stream>>>(
      meta, perm, hg, WgT, bg, g_head, g_var);
}